// Round 6
// baseline (186.294 us; speedup 1.0000x reference)
//
#include <hip/hip_runtime.h>
#include <hip/hip_bf16.h>
#include <stdint.h>

#define Hdim 512
#define KC   32768

typedef __hip_bfloat16 bf16;
typedef __attribute__((ext_vector_type(8))) short short8;
typedef __attribute__((ext_vector_type(4))) float float4v;
typedef __attribute__((ext_vector_type(4))) unsigned int uint4v;

// pack two fp32 -> two bf16 (truncation) in one v_perm_b32; low16 = trunc(e0)
__device__ __forceinline__ unsigned int pack_bf16_trunc(float e0, float e1) {
  union { float f; unsigned int u; } a, b;
  a.f = e0; b.f = e1;
  return __builtin_amdgcn_perm(b.u, a.u, 0x07060302u);
}

// ---------------- launch 1: prep partials (blocks 0..127) + WT transpose (128..191) ----
// prep: block (jt = b&31, dc = b>>5): 64 outputs x 128-deep d-chunk -> part[dc][j]
__global__ __launch_bounds__(256) void prep_wt_kernel(
    const float* __restrict__ input_, const float* __restrict__ h_0,
    const float* __restrict__ w_ih, const float* __restrict__ w_hh,
    const float* __restrict__ a_w_ih, const float* __restrict__ a_w_hh,
    float* __restrict__ gates_part, float* __restrict__ awi_part,
    bf16* __restrict__ wt) {
  const int t = threadIdx.x;
  if (blockIdx.x < 128) {
    __shared__ float h0s[128], ins[128];
    __shared__ float red[4][64];
    const int b = blockIdx.x;
    const int jt = b & 31, dc = b >> 5;
    const int lane = t & 63, wv = t >> 6;
    if (t < 128) { h0s[t] = h_0[dc * 128 + t]; ins[t] = input_[dc * 128 + t]; }
    __syncthreads();
    float acc = 0.f;
    if (jt < 24) {
      const int j = jt * 64 + lane;
#pragma unroll 4
      for (int i = 0; i < 32; ++i) {
        const int dl = wv * 32 + i;
        const size_t d = dc * 128 + dl;
        acc += h0s[dl] * w_hh[d * 1536 + j] + ins[dl] * w_ih[d * 1536 + j];
      }
    } else {
      const int j = (jt - 24) * 64 + lane;
#pragma unroll 4
      for (int i = 0; i < 32; ++i) {
        const int dl = wv * 32 + i;
        const size_t d = dc * 128 + dl;
        acc += ins[dl] * a_w_ih[d * Hdim + j];
      }
    }
    red[wv][lane] = acc;
    __syncthreads();
    if (t < 64) {
      float s = red[0][t] + red[1][t] + red[2][t] + red[3][t];
      if (jt < 24) gates_part[dc * 1536 + jt * 64 + t] = s;
      else         awi_part[dc * Hdim + (jt - 24) * 64 + t] = s;
    }
  } else {
    __shared__ float tile[64][65];
    const int b = blockIdx.x - 128;
    const int d0 = (b & 7) * 64, h0 = (b >> 3) * 64;
    const int tx = t & 63, tw = t >> 6;
#pragma unroll
    for (int r = 0; r < 16; ++r) {
      const int row = r * 4 + tw;
      tile[row][tx] = a_w_hh[(size_t)(d0 + row) * Hdim + h0 + tx];
    }
    __syncthreads();
#pragma unroll
    for (int r = 0; r < 16; ++r) {
      const int row = r * 4 + tw;
      wt[(size_t)(h0 + row) * Hdim + d0 + tx] = __float2bfloat16(tile[tx][row]);
    }
  }
}

// ---------------- launch 2: barrier-free wave-private fused GEMM + reduce ----------------
// 4096 blocks x 64 threads (1 wave). Wave owns 64m x 64n, BK=32, 16 k-chunks.
// No s_barrier anywhere: LDS is wave-private, only in-wave lgkmcnt ordering.
// XCD grouping: m-tile mg's 8 n-sharers have the same id&7 -> same XCD (A L2 reuse).
__global__ __launch_bounds__(64, 4) void gemm_reduce_kernel(
    const float* __restrict__ c_input, const bf16* __restrict__ WT,
    const float* __restrict__ awi_part,
    float* __restrict__ pw, float* __restrict__ pwc) {
  __shared__ __align__(16) char AsB[64 * 64];   // 64 rows x 32 bf16 (64 B/row), swizzled
  __shared__ __align__(16) char BsB[64 * 64];

  const int lane = threadIdx.x;
  const int lm = lane & 15, lq = lane >> 4;
  const int id = blockIdx.x;
  const int mg = ((id >> 6) << 3) | (id & 7);   // 0..511
  const int ng = (id >> 3) & 7;                 // 0..7
  const int m0 = mg * 64, n0 = ng * 64;

  // staging mapping: 4 rounds of 16 rows; lane -> (row-in-round, granule)
  const int sr = lane >> 2;   // 0..15
  const int sg = lane & 3;    // 16B granule within 64B row

  float4v acc[4][4];
#pragma unroll
  for (int i = 0; i < 4; ++i)
#pragma unroll
    for (int j = 0; j < 4; ++j)
      acc[i][j] = (float4v){0.f, 0.f, 0.f, 0.f};

#pragma unroll 2
  for (int kc = 0; kc < 16; ++kc) {
    const int k0 = kc * 32;
    // stage A: fp32 -> bf16 trunc -> swizzled private LDS
#pragma unroll
    for (int r = 0; r < 4; ++r) {
      const int row = r * 16 + sr;
      const float* p = c_input + (size_t)(m0 + row) * Hdim + k0 + sg * 8;
      float4v v0 = *(const float4v*)p;
      float4v v1 = *(const float4v*)(p + 4);
      uint4v u;
      u[0] = pack_bf16_trunc(v0[0], v0[1]);
      u[1] = pack_bf16_trunc(v0[2], v0[3]);
      u[2] = pack_bf16_trunc(v1[0], v1[1]);
      u[3] = pack_bf16_trunc(v1[2], v1[3]);
      *(uint4v*)(AsB + row * 64 + ((sg ^ (row & 3)) << 4)) = u;
    }
    // stage B: bf16 granules -> swizzled private LDS
#pragma unroll
    for (int r = 0; r < 4; ++r) {
      const int row = r * 16 + sr;
      *(short8*)(BsB + row * 64 + ((sg ^ (row & 3)) << 4)) =
          *(const short8*)(WT + (size_t)(n0 + row) * Hdim + k0 + sg * 8);
    }
    // fragments (row&3 == lm&3 since tile offsets are multiples of 16)
    short8 a[4], b[4];
#pragma unroll
    for (int mt = 0; mt < 4; ++mt)
      a[mt] = *(const short8*)(AsB + (mt * 16 + lm) * 64 + ((lq ^ (lm & 3)) << 4));
#pragma unroll
    for (int nt = 0; nt < 4; ++nt)
      b[nt] = *(const short8*)(BsB + (nt * 16 + lm) * 64 + ((lq ^ (lm & 3)) << 4));
#pragma unroll
    for (int mt = 0; mt < 4; ++mt)
#pragma unroll
      for (int nt = 0; nt < 4; ++nt)
        acc[mt][nt] = __builtin_amdgcn_mfma_f32_16x16x32_bf16(a[mt], b[nt], acc[mt][nt], 0, 0, 0);
  }

  // epilogue: alpha = sigmoid(acc + awi[n]); accumulate exp(alpha), exp(alpha)*c
#pragma unroll
  for (int nt = 0; nt < 4; ++nt) {
    const int n = n0 + nt * 16 + lm;
    float aw = awi_part[n] + awi_part[Hdim + n] + awi_part[2 * Hdim + n] + awi_part[3 * Hdim + n];
    float sw = 0.f, swc = 0.f;
#pragma unroll
    for (int mt = 0; mt < 4; ++mt) {
      const int mrow = m0 + mt * 16 + lq * 4;
#pragma unroll
      for (int r = 0; r < 4; ++r) {
        float v = acc[mt][nt][r] + aw;
        float alpha = 1.f / (1.f + __expf(-v));
        float e = __expf(alpha);
        float c = c_input[(size_t)(mrow + r) * Hdim + n];  // L2-hot (same XCD)
        sw  += e;
        swc += e * c;
      }
    }
    sw  += __shfl_xor(sw, 16, 64);
    sw  += __shfl_xor(sw, 32, 64);
    swc += __shfl_xor(swc, 16, 64);
    swc += __shfl_xor(swc, 32, 64);
    if (lq == 0) {
      pw[(size_t)mg * Hdim + n]  = sw;
      pwc[(size_t)mg * Hdim + n] = swc;
    }
  }
}

// ---------------- launch 3: final reduction + LSTM merge ----------------
// 8 blocks x 1024: block covers 64 h; 16-way split over 512 m-slabs
__global__ __launch_bounds__(1024) void finalize_kernel(
    const float* __restrict__ pw, const float* __restrict__ pwc,
    const float* __restrict__ gates_part, const float* __restrict__ bias,
    float* __restrict__ out) {
  __shared__ float rsw[16][64], rswc[16][64];
  const int t = threadIdx.x;
  const int hl = t & 63, q = t >> 6;
  const int hh = blockIdx.x * 64 + hl;
  float sw = 0.f, swc = 0.f;
#pragma unroll 8
  for (int kb = q * 32; kb < q * 32 + 32; ++kb) {
    sw  += pw[(size_t)kb * Hdim + hh];
    swc += pwc[(size_t)kb * Hdim + hh];
  }
  rsw[q][hl] = sw; rswc[q][hl] = swc;
  __syncthreads();
  if (t < 64) {
    const int h = blockIdx.x * 64 + t;
    sw = 0.f; swc = 0.f;
#pragma unroll
    for (int qq = 0; qq < 16; ++qq) { sw += rsw[qq][t]; swc += rswc[qq][t]; }
    float ipre = gates_part[h] + gates_part[1536 + h] + gates_part[2 * 1536 + h]
               + gates_part[3 * 1536 + h] + bias[h];
    float opre = gates_part[Hdim + h] + gates_part[1536 + Hdim + h]
               + gates_part[2 * 1536 + Hdim + h] + gates_part[3 * 1536 + Hdim + h]
               + bias[Hdim + h];
    float gpre = gates_part[2 * Hdim + h] + gates_part[1536 + 2 * Hdim + h]
               + gates_part[2 * 1536 + 2 * Hdim + h] + gates_part[3 * 1536 + 2 * Hdim + h]
               + bias[2 * Hdim + h];
    float ei = expf(1.f / (1.f + expf(-ipre)));   // exp(sigmoid(i))
    float g  = tanhf(gpre);
    float o  = 1.f / (1.f + expf(-opre));
    float denom = ei + sw + 1e-12f;
    float c1 = (ei * g + swc) / denom;
    float h1 = o * tanhf(c1);
    out[h]        = h1;
    out[Hdim + h] = c1;
  }
}

extern "C" void kernel_launch(void* const* d_in, const int* in_sizes, int n_in,
                              void* d_out, int out_size, void* d_ws, size_t ws_size,
                              hipStream_t stream) {
  const float* input_  = (const float*)d_in[0];
  const float* c_input = (const float*)d_in[1];
  const float* h_0     = (const float*)d_in[2];
  /* d_in[3] = c_0: unused by the reference's taken branch */
  const float* w_ih    = (const float*)d_in[4];
  const float* w_hh    = (const float*)d_in[5];
  const float* bias    = (const float*)d_in[6];
  const float* a_w_ih  = (const float*)d_in[7];
  const float* a_w_hh  = (const float*)d_in[8];

  char* ws = (char*)d_ws;
  float* pw         = (float*)ws;                             // 512*512 f32 = 1 MB
  float* pwc        = (float*)(ws + 1024 * 1024);             // 1 MB
  float* gates_part = (float*)(ws + 2 * 1024 * 1024);         // 4*1536*4 = 24 KB
  float* awi_part   = (float*)(ws + 2 * 1024 * 1024 + 24576); // 4*512*4 = 8 KB
  bf16*  WT         = (bf16*)(ws + 2 * 1024 * 1024 + 32768);  // 512 KB

  hipLaunchKernelGGL(prep_wt_kernel, dim3(192), dim3(256), 0, stream,
                     input_, h_0, w_ih, w_hh, a_w_ih, a_w_hh, gates_part, awi_part, WT);
  hipLaunchKernelGGL(gemm_reduce_kernel, dim3(4096), dim3(64), 0, stream,
                     c_input, WT, awi_part, pw, pwc);
  hipLaunchKernelGGL(finalize_kernel, dim3(8), dim3(1024), 0, stream,
                     pw, pwc, gates_part, bias, (float*)d_out);
}